// Round 9
// baseline (1422.807 us; speedup 1.0000x reference)
//
#include <hip/hip_runtime.h>

#define HH   64
#define BPTS 256          // points per block/chunk
#define LPB  4096         // points per batch
#define NBAT 256
#define NPTS (NBAT * LPB) // 1,048,576 points

typedef _Float16 f16x8 __attribute__((ext_vector_type(8)));
typedef float    f32x4 __attribute__((ext_vector_type(4)));

union HL { unsigned u; _Float16 f[2]; };

// ---------- swizzled addressing for a [R][64] f16 plane (16B-block XOR)
__device__ __forceinline__ int bofs(int r, int m) {
    return (r << 6) | ((m ^ (r & 7)) << 3);
}
__device__ __forceinline__ int fofs(int r, int c) {
    return (r << 6) | ((((c >> 3) ^ (r & 7))) << 3) | (c & 7);
}
__device__ __forceinline__ f16x8 rd8(const _Float16* p, int r, int m) {
    return *(const f16x8*)&p[bofs(r, m)];
}

// ---------- split-f16: v ~= hi + lo, |v-(hi+lo)| <= 2^-22 |v|
__device__ __forceinline__ void split2(float v, _Float16& h, _Float16& l) {
    h = (_Float16)v;
    l = (_Float16)(v - (float)h);
}
__device__ __forceinline__ unsigned pack_hilo(float v) {
    HL u; split2(v, u.f[0], u.f[1]); return u.u;
}

// ---------- 32x64x64 GEMM tile per wave via MFMA, 3-term split-f16
__device__ __forceinline__ void mfma_gemm(const _Float16* ah_, const _Float16* al_,
                                          const _Float16* wh_, const _Float16* wl_,
                                          int rb, int lane, f32x4 acc[2][4]) {
    const int rA = rb + (lane & 15);
    const int cB = lane & 15;
    const int g  = lane >> 4;
#pragma unroll
    for (int s = 0; s < 2; ++s) {
        const int m = s * 4 + g;
        f16x8 Ah[2], Al[2];
#pragma unroll
        for (int rt = 0; rt < 2; ++rt) {
            Ah[rt] = rd8(ah_, rA + 16 * rt, m);
            Al[rt] = rd8(al_, rA + 16 * rt, m);
        }
#pragma unroll
        for (int ct = 0; ct < 4; ++ct) {
            f16x8 Bh = rd8(wh_, cB + 16 * ct, m);
            f16x8 Bl = rd8(wl_, cB + 16 * ct, m);
#pragma unroll
            for (int rt = 0; rt < 2; ++rt) {
                acc[rt][ct] = __builtin_amdgcn_mfma_f32_16x16x32_f16(Ah[rt], Bh, acc[rt][ct], 0, 0, 0);
                acc[rt][ct] = __builtin_amdgcn_mfma_f32_16x16x32_f16(Ah[rt], Bl, acc[rt][ct], 0, 0, 0);
                acc[rt][ct] = __builtin_amdgcn_mfma_f32_16x16x32_f16(Al[rt], Bh, acc[rt][ct], 0, 0, 0);
            }
        }
    }
}

// ---------- write activations (C/D layout: row=rb+16rt+4g+reg, col=16ct+(lane&15))
__device__ __forceinline__ void write_acts(_Float16* hi, _Float16* lo,
                                           const f32x4 t[2][4], int rb, int lane) {
    const int g = lane >> 4, cb = lane & 15;
#pragma unroll
    for (int rt = 0; rt < 2; ++rt)
#pragma unroll
        for (int reg = 0; reg < 4; ++reg) {
            const int r = rb + 16 * rt + 4 * g + reg;
#pragma unroll
            for (int ct = 0; ct < 4; ++ct) {
                _Float16 h, l;
                split2(t[rt][ct][reg], h, l);
                const int o = fofs(r, 16 * ct + cb);
                hi[o] = h; lo[o] = l;
            }
        }
}

// ---------- stage 64x64 fp32 weight tile -> hi/lo planes (512 threads)
__device__ __forceinline__ void stage_w(_Float16* wh, _Float16* wl,
                                        const float* __restrict__ W, int tid, int ldw) {
    const int o = tid >> 3, k0 = (tid & 7) << 3;
    const float* wr = &W[(size_t)o * ldw + k0];
    float4 a = *(const float4*)wr;
    float4 b = *(const float4*)(wr + 4);
    float v[8] = {a.x, a.y, a.z, a.w, b.x, b.y, b.z, b.w};
    f16x8 h, l;
#pragma unroll
    for (int i = 0; i < 8; ++i) { _Float16 hh, ll; split2(v[i], hh, ll); h[i] = hh; l[i] = ll; }
    const int ofs = bofs(o, k0 >> 3);
    *(f16x8*)&wh[ofs] = h;
    *(f16x8*)&wl[ofs] = l;
}

// ---------- stage packed-u32 activations (global u) -> hi/lo LDS planes (512 thr)
__device__ __forceinline__ void stage_u(_Float16* hi, _Float16* lo,
                                        const unsigned* __restrict__ u,
                                        int pbase, int tid) {
    const int row = tid >> 1, c0 = (tid & 1) << 5;
    const unsigned* src = &u[(size_t)(pbase + row) * HH + c0];
#pragma unroll
    for (int j = 0; j < 4; ++j) {
        uint4 qa = *(const uint4*)&src[j * 8];
        uint4 qb = *(const uint4*)&src[j * 8 + 4];
        unsigned q[8] = {qa.x, qa.y, qa.z, qa.w, qb.x, qb.y, qb.z, qb.w};
        f16x8 h, l;
#pragma unroll
        for (int i = 0; i < 8; ++i) { HL v; v.u = q[i]; h[i] = v.f[0]; l[i] = v.f[1]; }
        const int ofs = bofs(row, (c0 >> 3) + j);
        *(f16x8*)&hi[ofs] = h;
        *(f16x8*)&lo[ofs] = l;
    }
}

// ---------- per-wave goff: lane computes goff[lane]; consumers shfl
__device__ __forceinline__ float goff_lane_calc(const float* __restrict__ gall,
                                                const float* __restrict__ gw,
                                                const float* __restrict__ gb,
                                                int li, int b, int lane) {
    const float* gr = &gall[((size_t)li * NBAT + b) * HH];
    const float* wr = &gw[((size_t)li * 64 + lane) * 128 + 64];
    float s = gb[li * 64 + lane];
#pragma unroll
    for (int k = 0; k < 64; k += 4) {
        float4 w4 = *(const float4*)&wr[k];
        float4 g4 = *(const float4*)&gr[k];
        s = fmaf(g4.x, w4.x, fmaf(g4.y, w4.y, fmaf(g4.z, w4.z, fmaf(g4.w, w4.w, s))));
    }
    return s;
}

// ---------- order-preserving float<->uint encoding
__device__ __forceinline__ unsigned encf(float f) {
    unsigned u = __float_as_uint(f);
    return (u & 0x80000000u) ? ~u : (u | 0x80000000u);
}
__device__ __forceinline__ float decf(unsigned u) {
    return (u & 0x80000000u) ? __uint_as_float(u ^ 0x80000000u) : __uint_as_float(~u);
}

__global__ __launch_bounds__(256) void k_init(float* gbuf, unsigned* oenc) {
    int i = blockIdx.x * 256 + threadIdx.x;
    if (i < 4 * NBAT * HH) gbuf[i] = 0.0f;
    if (i < NBAT * HH)     oenc[i] = 0x007FFFFFu; // encf(-inf)
}

// ================= shared building blocks (inside kernels) =================
// proj_in prologue: 2 threads/point, writes a planes
#define PROJ_IN_PROLOGUE()                                                      \
    {                                                                           \
        const int p = tid >> 1, half = tid & 1;                                 \
        const size_t pidx = (size_t)(pbase + p) * 3;                            \
        const float x0 = x[pidx], x1 = x[pidx + 1], x2 = x[pidx + 2];           \
        for (int j = 0; j < 4; ++j) {                                           \
            const int o0 = half * 32 + j * 8;                                   \
            f16x8 h, l;                                                         \
            for (int i = 0; i < 8; ++i) {                                       \
                const int o = o0 + i;                                           \
                float v = fmaxf(fmaf(piw[o * 3], x0,                            \
                              fmaf(piw[o * 3 + 1], x1,                          \
                              fmaf(piw[o * 3 + 2], x2, pib[o]))), 0.0f);        \
                _Float16 hh, ll; split2(v, hh, ll);                             \
                h[i] = hh; l[i] = ll;                                           \
            }                                                                   \
            const int ofs = bofs(p, o0 >> 3);                                   \
            *(f16x8*)&a_hi[ofs] = h;                                            \
            *(f16x8*)&a_lo[ofs] = l;                                            \
        }                                                                       \
    }

// epilogue: reduce m4 (per-thread 4 channels) across lanes+waves, then atomic
#define MAX_EPILOGUE(ATOMIC_STMT)                                               \
    {                                                                           \
        for (int ct = 0; ct < 4; ++ct) {                                        \
            m4[ct] = fmaxf(m4[ct], __shfl_xor(m4[ct], 16, 64));                 \
            m4[ct] = fmaxf(m4[ct], __shfl_xor(m4[ct], 32, 64));                 \
        }                                                                       \
        __syncthreads();                                                        \
        float* red = (float*)a_hi;                                              \
        if ((lane >> 4) == 0)                                                   \
            for (int ct = 0; ct < 4; ++ct)                                      \
                red[wave * 64 + ct * 16 + (lane & 15)] = m4[ct];                \
        __syncthreads();                                                        \
        if (tid < 64) {                                                         \
            float v = red[tid];                                                 \
            for (int w = 1; w < 8; ++w) v = fmaxf(v, red[w * 64 + tid]);        \
            ATOMIC_STMT;                                                        \
        }                                                                       \
    }

// ======================= stored-u pipeline kernels =======================

// P0: proj_in + lyr0 -> store u0 (packed split-f16), g0-max
__global__ __launch_bounds__(512, 4) void k_p0s(
    const float* __restrict__ x, const float* __restrict__ piw,
    const float* __restrict__ pib, const float* __restrict__ lyrw,
    const float* __restrict__ lyrb, unsigned* __restrict__ u,
    float* __restrict__ gout) {
    __shared__ __align__(16) _Float16 a_hi[BPTS * HH];
    __shared__ __align__(16) _Float16 a_lo[BPTS * HH];
    __shared__ __align__(16) _Float16 w_hi[HH * HH];
    __shared__ __align__(16) _Float16 w_lo[HH * HH];
    const int tid = threadIdx.x, lane = tid & 63, wave = tid >> 6;
    const int rb = wave << 5;
    const int pbase = blockIdx.x * BPTS;
    const int b = pbase / LPB;
    int ch4[4];
#pragma unroll
    for (int ct = 0; ct < 4; ++ct) ch4[ct] = 16 * ct + (lane & 15);

    stage_w(w_hi, w_lo, lyrw, tid, 64);
    PROJ_IN_PROLOGUE();
    __syncthreads();

    f32x4 acc[2][4];
#pragma unroll
    for (int rt = 0; rt < 2; ++rt)
#pragma unroll
        for (int ct = 0; ct < 4; ++ct) {
            const float bb = lyrb[ch4[ct]];
            acc[rt][ct] = (f32x4){bb, bb, bb, bb};
        }
    mfma_gemm(a_hi, a_lo, w_hi, w_lo, rb, lane, acc);

    const int g = lane >> 4;
    float m4[4] = {0.f, 0.f, 0.f, 0.f};
#pragma unroll
    for (int rt = 0; rt < 2; ++rt)
#pragma unroll
        for (int reg = 0; reg < 4; ++reg) {
            const int r = rb + 16 * rt + 4 * g + reg;
            unsigned* dst = &u[(size_t)(pbase + r) * HH];
#pragma unroll
            for (int ct = 0; ct < 4; ++ct) {
                float v = fmaxf(acc[rt][ct][reg], 0.0f);
                m4[ct] = fmaxf(m4[ct], v);
                dst[ch4[ct]] = pack_hilo(v);
            }
        }
    MAX_EPILOGUE(atomicMax((unsigned*)&gout[b * HH + tid], __float_as_uint(v)));
}

// Mid (stored-u): read u_li -> glyr_li -> x_li; [pout_li -> partial]; lyr_{li+1} -> u, g
template<bool DO_POUT>
__global__ __launch_bounds__(512, 4) void k_midS(
    unsigned* __restrict__ u, float* __restrict__ partial,
    const float* __restrict__ gall, float* __restrict__ gout,
    const float* __restrict__ gw, const float* __restrict__ gb,
    const float* __restrict__ lyrw, const float* __restrict__ lyrb,
    const float* __restrict__ pw, int li, int accflag) {
    __shared__ __align__(16) _Float16 a_hi[BPTS * HH];
    __shared__ __align__(16) _Float16 a_lo[BPTS * HH];
    __shared__ __align__(16) _Float16 w_hi[HH * HH];
    __shared__ __align__(16) _Float16 w_lo[HH * HH];
    const int tid = threadIdx.x, lane = tid & 63, wave = tid >> 6;
    const int rb = wave << 5;
    const int pbase = blockIdx.x * BPTS;
    const int b = pbase / LPB;
    const int g = lane >> 4;
    int ch4[4];
#pragma unroll
    for (int ct = 0; ct < 4; ++ct) ch4[ct] = 16 * ct + (lane & 15);

    stage_u(a_hi, a_lo, u, pbase, tid);
    stage_w(w_hi, w_lo, &gw[(size_t)li * 64 * 128], tid, 128);
    const float gl = goff_lane_calc(gall, gw, gb, li, b, lane);
    __syncthreads();

    f32x4 a2[2][4];
#pragma unroll
    for (int ct = 0; ct < 4; ++ct) {
        const float gv = __shfl(gl, ch4[ct], 64);
#pragma unroll
        for (int rt = 0; rt < 2; ++rt) a2[rt][ct] = (f32x4){gv, gv, gv, gv};
    }
    mfma_gemm(a_hi, a_lo, w_hi, w_lo, rb, lane, a2);
#pragma unroll
    for (int rt = 0; rt < 2; ++rt)
#pragma unroll
        for (int ct = 0; ct < 4; ++ct)
#pragma unroll
            for (int r = 0; r < 4; ++r)
                a2[rt][ct][r] = fmaxf(a2[rt][ct][r], 0.0f);   // x_li
    __syncthreads();

    write_acts(a_hi, a_lo, a2, rb, lane);
    if (DO_POUT) {
        stage_w(w_hi, w_lo, &pw[(size_t)li * 64], tid, 256);
        __syncthreads();
        f32x4 oacc[2][4];
#pragma unroll
        for (int rt = 0; rt < 2; ++rt)
#pragma unroll
            for (int ct = 0; ct < 4; ++ct) oacc[rt][ct] = (f32x4){0.f, 0.f, 0.f, 0.f};
        mfma_gemm(a_hi, a_lo, w_hi, w_lo, rb, lane, oacc);
#pragma unroll
        for (int rt = 0; rt < 2; ++rt)
#pragma unroll
            for (int reg = 0; reg < 4; ++reg) {
                const int r = rb + 16 * rt + 4 * g + reg;
                float* pr = &partial[(size_t)(pbase + r) * HH];
#pragma unroll
                for (int ct = 0; ct < 4; ++ct) {
                    float v = oacc[rt][ct][reg];
                    if (accflag) v += pr[ch4[ct]];
                    pr[ch4[ct]] = v;
                }
            }
        __syncthreads();                 // w reads done before restage
        stage_w(w_hi, w_lo, &lyrw[(size_t)(li + 1) * 4096], tid, 64);
        __syncthreads();
    } else {
        stage_w(w_hi, w_lo, &lyrw[(size_t)(li + 1) * 4096], tid, 64);
        __syncthreads();
    }

    f32x4 acc[2][4];
#pragma unroll
    for (int rt = 0; rt < 2; ++rt)
#pragma unroll
        for (int ct = 0; ct < 4; ++ct) {
            const float bb = lyrb[(li + 1) * 64 + ch4[ct]];
            acc[rt][ct] = (f32x4){bb, bb, bb, bb};
        }
    mfma_gemm(a_hi, a_lo, w_hi, w_lo, rb, lane, acc);

    float m4[4] = {0.f, 0.f, 0.f, 0.f};
#pragma unroll
    for (int rt = 0; rt < 2; ++rt)
#pragma unroll
        for (int reg = 0; reg < 4; ++reg) {
            const int r = rb + 16 * rt + 4 * g + reg;
            unsigned* dst = &u[(size_t)(pbase + r) * HH];
#pragma unroll
            for (int ct = 0; ct < 4; ++ct) {
                float v = fmaxf(acc[rt][ct][reg], 0.0f);
                m4[ct] = fmaxf(m4[ct], v);
                dst[ch4[ct]] = pack_hilo(v);
            }
        }
    MAX_EPILOGUE(atomicMax((unsigned*)&gout[b * HH + tid], __float_as_uint(v)));
}

// Last (stored-u full): read u_3 -> glyr3 -> x_3 -> pout3 + partial + pob -> oenc
__global__ __launch_bounds__(512, 4) void k_lastS(
    const unsigned* __restrict__ u, const float* __restrict__ partial,
    const float* __restrict__ gall, const float* __restrict__ gw,
    const float* __restrict__ gb, const float* __restrict__ pw,
    const float* __restrict__ pob, unsigned* __restrict__ oenc) {
    __shared__ __align__(16) _Float16 a_hi[BPTS * HH];
    __shared__ __align__(16) _Float16 a_lo[BPTS * HH];
    __shared__ __align__(16) _Float16 w_hi[HH * HH];
    __shared__ __align__(16) _Float16 w_lo[HH * HH];
    const int tid = threadIdx.x, lane = tid & 63, wave = tid >> 6;
    const int rb = wave << 5;
    const int pbase = blockIdx.x * BPTS;
    const int b = pbase / LPB;
    const int g = lane >> 4;
    const int li = 3;
    int ch4[4];
#pragma unroll
    for (int ct = 0; ct < 4; ++ct) ch4[ct] = 16 * ct + (lane & 15);

    stage_u(a_hi, a_lo, u, pbase, tid);
    stage_w(w_hi, w_lo, &gw[(size_t)li * 64 * 128], tid, 128);
    const float gl = goff_lane_calc(gall, gw, gb, li, b, lane);
    __syncthreads();

    f32x4 a2[2][4];
#pragma unroll
    for (int ct = 0; ct < 4; ++ct) {
        const float gv = __shfl(gl, ch4[ct], 64);
#pragma unroll
        for (int rt = 0; rt < 2; ++rt) a2[rt][ct] = (f32x4){gv, gv, gv, gv};
    }
    mfma_gemm(a_hi, a_lo, w_hi, w_lo, rb, lane, a2);
#pragma unroll
    for (int rt = 0; rt < 2; ++rt)
#pragma unroll
        for (int ct = 0; ct < 4; ++ct)
#pragma unroll
            for (int r = 0; r < 4; ++r)
                a2[rt][ct][r] = fmaxf(a2[rt][ct][r], 0.0f);
    __syncthreads();

    write_acts(a_hi, a_lo, a2, rb, lane);
    stage_w(w_hi, w_lo, &pw[(size_t)li * 64], tid, 256);
    __syncthreads();

    f32x4 oacc[2][4];
#pragma unroll
    for (int rt = 0; rt < 2; ++rt)
#pragma unroll
        for (int ct = 0; ct < 4; ++ct) oacc[rt][ct] = (f32x4){0.f, 0.f, 0.f, 0.f};
    mfma_gemm(a_hi, a_lo, w_hi, w_lo, rb, lane, oacc);

    float m4[4] = {-3.4e38f, -3.4e38f, -3.4e38f, -3.4e38f};
#pragma unroll
    for (int rt = 0; rt < 2; ++rt)
#pragma unroll
        for (int reg = 0; reg < 4; ++reg) {
            const int r = rb + 16 * rt + 4 * g + reg;
            const float* pr = &partial[(size_t)(pbase + r) * HH];
#pragma unroll
            for (int ct = 0; ct < 4; ++ct)
                m4[ct] = fmaxf(m4[ct], oacc[rt][ct][reg] + pr[ch4[ct]]);
        }
    MAX_EPILOGUE(atomicMax(&oenc[b * HH + tid], encf(v + pob[tid])));
}

// ======================= recompute ladder (fallback / hybrid final) =======================

template<int NSTAGE, bool DO_OUT>
__global__ __launch_bounds__(512, 4) void k_fused(
    const float* __restrict__ x, const float* __restrict__ piw,
    const float* __restrict__ pib, const float* __restrict__ lyrw,
    const float* __restrict__ lyrb, const float* __restrict__ gw,
    const float* __restrict__ gb, const float* __restrict__ pw,
    const float* __restrict__ pob, const float* __restrict__ gall,
    float* __restrict__ gmax, unsigned* __restrict__ oenc) {
    __shared__ __align__(16) _Float16 a_hi[BPTS * HH];
    __shared__ __align__(16) _Float16 a_lo[BPTS * HH];
    __shared__ __align__(16) _Float16 w_hi[HH * HH];
    __shared__ __align__(16) _Float16 w_lo[HH * HH];
    const int tid = threadIdx.x, lane = tid & 63, wave = tid >> 6;
    const int rb = wave << 5;
    const int pbase = blockIdx.x * BPTS;
    const int b = pbase / LPB;
    int ch4[4];
#pragma unroll
    for (int ct = 0; ct < 4; ++ct) ch4[ct] = 16 * ct + (lane & 15);

    stage_w(w_hi, w_lo, lyrw, tid, 64);
    PROJ_IN_PROLOGUE();
    __syncthreads();

    f32x4 acc[2][4];
#pragma unroll
    for (int rt = 0; rt < 2; ++rt)
#pragma unroll
        for (int ct = 0; ct < 4; ++ct) {
            const float bb = lyrb[ch4[ct]];
            acc[rt][ct] = (f32x4){bb, bb, bb, bb};
        }
    mfma_gemm(a_hi, a_lo, w_hi, w_lo, rb, lane, acc);

    f32x4 oacc[2][4];
    if (DO_OUT) {
#pragma unroll
        for (int rt = 0; rt < 2; ++rt)
#pragma unroll
            for (int ct = 0; ct < 4; ++ct) oacc[rt][ct] = (f32x4){0.f, 0.f, 0.f, 0.f};
    }

    constexpr int NITER = DO_OUT ? 4 : (NSTAGE - 1);
#pragma unroll
    for (int li = 0; li < NITER; ++li) {
#pragma unroll
        for (int rt = 0; rt < 2; ++rt)
#pragma unroll
            for (int ct = 0; ct < 4; ++ct)
#pragma unroll
                for (int r = 0; r < 4; ++r)
                    acc[rt][ct][r] = fmaxf(acc[rt][ct][r], 0.0f);

        __syncthreads();
        write_acts(a_hi, a_lo, acc, rb, lane);
        stage_w(w_hi, w_lo, &gw[(size_t)li * 64 * 128], tid, 128);
        const float gl = goff_lane_calc(gall, gw, gb, li, b, lane);
        __syncthreads();

        f32x4 a2[2][4];
#pragma unroll
        for (int ct = 0; ct < 4; ++ct) {
            const float gv = __shfl(gl, ch4[ct], 64);
#pragma unroll
            for (int rt = 0; rt < 2; ++rt) a2[rt][ct] = (f32x4){gv, gv, gv, gv};
        }
        mfma_gemm(a_hi, a_lo, w_hi, w_lo, rb, lane, a2);
#pragma unroll
        for (int rt = 0; rt < 2; ++rt)
#pragma unroll
            for (int ct = 0; ct < 4; ++ct)
#pragma unroll
                for (int r = 0; r < 4; ++r)
                    a2[rt][ct][r] = fmaxf(a2[rt][ct][r], 0.0f);

        __syncthreads();
        write_acts(a_hi, a_lo, a2, rb, lane);
        if (DO_OUT) {
            stage_w(w_hi, w_lo, &pw[(size_t)li * 64], tid, 256);
            __syncthreads();
            mfma_gemm(a_hi, a_lo, w_hi, w_lo, rb, lane, oacc);
            if (li < 3) {
                __syncthreads();
                stage_w(w_hi, w_lo, &lyrw[(size_t)(li + 1) * 4096], tid, 64);
                __syncthreads();
            }
        } else {
            stage_w(w_hi, w_lo, &lyrw[(size_t)(li + 1) * 4096], tid, 64);
            __syncthreads();
        }
        if (li < 3) {
#pragma unroll
            for (int rt = 0; rt < 2; ++rt)
#pragma unroll
                for (int ct = 0; ct < 4; ++ct) {
                    const float bb = lyrb[(li + 1) * 64 + ch4[ct]];
                    acc[rt][ct] = (f32x4){bb, bb, bb, bb};
                }
            mfma_gemm(a_hi, a_lo, w_hi, w_lo, rb, lane, acc);
        }
    }

    float m4[4];
    if (!DO_OUT) {
#pragma unroll
        for (int ct = 0; ct < 4; ++ct) m4[ct] = 0.0f;
#pragma unroll
        for (int rt = 0; rt < 2; ++rt)
#pragma unroll
            for (int ct = 0; ct < 4; ++ct)
#pragma unroll
                for (int r = 0; r < 4; ++r)
                    m4[ct] = fmaxf(m4[ct], fmaxf(acc[rt][ct][r], 0.0f));
        MAX_EPILOGUE(atomicMax((unsigned*)&gmax[b * HH + tid], __float_as_uint(v)));
    } else {
#pragma unroll
        for (int ct = 0; ct < 4; ++ct) m4[ct] = -3.4e38f;
#pragma unroll
        for (int rt = 0; rt < 2; ++rt)
#pragma unroll
            for (int ct = 0; ct < 4; ++ct)
#pragma unroll
                for (int r = 0; r < 4; ++r)
                    m4[ct] = fmaxf(m4[ct], oacc[rt][ct][r]);
        MAX_EPILOGUE(atomicMax(&oenc[b * HH + tid], encf(v + pob[tid])));
    }
}

__global__ __launch_bounds__(256) void k_dec(const unsigned* __restrict__ oenc,
                                             float* __restrict__ out) {
    int i = blockIdx.x * 256 + threadIdx.x;
    out[i] = decf(oenc[i]);
}

extern "C" void kernel_launch(void* const* d_in, const int* in_sizes, int n_in,
                              void* d_out, int out_size, void* d_ws, size_t ws_size,
                              hipStream_t stream) {
    const float* x    = (const float*)d_in[0];
    const float* piw  = (const float*)d_in[1];
    const float* pib  = (const float*)d_in[2];
    const float* lyrw = (const float*)d_in[3];
    const float* lyrb = (const float*)d_in[4];
    const float* gw   = (const float*)d_in[5];
    const float* gb   = (const float*)d_in[6];
    const float* pw   = (const float*)d_in[7];
    const float* pob  = (const float*)d_in[8];
    float* out = (float*)d_out;

    const int nblk = NPTS / BPTS; // 4096
    const size_t UB    = (size_t)NPTS * HH * 4;      // u (packed u32): 256 MiB
    const size_t PB    = (size_t)NPTS * HH * 4;      // partial f32: 256 MiB
    const size_t SMALL = (size_t)5 * NBAT * HH * 4;  // g[4] + oenc
    const size_t NEED12 = UB + PB + SMALL;
    const size_t NEED19 = UB + SMALL;

    if (ws_size >= NEED12) {
        // ---- 12-unit stored-u pipeline: u | partial | g[4] | oenc
        unsigned* u    = (unsigned*)d_ws;
        float* partial = (float*)(u + (size_t)NPTS * HH);
        float* gbuf    = partial + (size_t)NPTS * HH;
        unsigned* oenc = (unsigned*)(gbuf + 4 * NBAT * HH);

        k_init<<<256, 256, 0, stream>>>(gbuf, oenc);
        k_p0s<<<nblk, 512, 0, stream>>>(x, piw, pib, lyrw, lyrb, u, gbuf);
        k_midS<true><<<nblk, 512, 0, stream>>>(u, partial, gbuf, gbuf + 1 * NBAT * HH,
                                               gw, gb, lyrw, lyrb, pw, 0, 0);
        k_midS<true><<<nblk, 512, 0, stream>>>(u, partial, gbuf, gbuf + 2 * NBAT * HH,
                                               gw, gb, lyrw, lyrb, pw, 1, 1);
        k_midS<true><<<nblk, 512, 0, stream>>>(u, partial, gbuf, gbuf + 3 * NBAT * HH,
                                               gw, gb, lyrw, lyrb, pw, 2, 1);
        k_lastS<<<nblk, 512, 0, stream>>>(u, partial, gbuf, gw, gb, pw, pob, oenc);
        k_dec<<<(NBAT * HH) / 256, 256, 0, stream>>>(oenc, out);
    } else if (ws_size >= NEED19) {
        // ---- 19-unit hybrid: u | g[4] | oenc ; final = full recompute kernel
        unsigned* u    = (unsigned*)d_ws;
        float* gbuf    = (float*)(u + (size_t)NPTS * HH);
        unsigned* oenc = (unsigned*)(gbuf + 4 * NBAT * HH);

        k_init<<<256, 256, 0, stream>>>(gbuf, oenc);
        k_p0s<<<nblk, 512, 0, stream>>>(x, piw, pib, lyrw, lyrb, u, gbuf);
        k_midS<false><<<nblk, 512, 0, stream>>>(u, nullptr, gbuf, gbuf + 1 * NBAT * HH,
                                                gw, gb, lyrw, lyrb, pw, 0, 0);
        k_midS<false><<<nblk, 512, 0, stream>>>(u, nullptr, gbuf, gbuf + 2 * NBAT * HH,
                                                gw, gb, lyrw, lyrb, pw, 1, 0);
        k_midS<false><<<nblk, 512, 0, stream>>>(u, nullptr, gbuf, gbuf + 3 * NBAT * HH,
                                                gw, gb, lyrw, lyrb, pw, 2, 0);
        k_fused<4, true><<<nblk, 512, 0, stream>>>(x, piw, pib, lyrw, lyrb, gw, gb, pw, pob,
                                                   gbuf, nullptr, oenc);
        k_dec<<<(NBAT * HH) / 256, 256, 0, stream>>>(oenc, out);
    } else {
        // ---- 28-unit recompute ladder (tiny ws): g[4] | oenc
        float* gbuf    = (float*)d_ws;
        unsigned* oenc = (unsigned*)(gbuf + 4 * NBAT * HH);

        k_init<<<256, 256, 0, stream>>>(gbuf, oenc);
        k_fused<1, false><<<nblk, 512, 0, stream>>>(x, piw, pib, lyrw, lyrb, gw, gb, pw, pob,
                                                    gbuf, gbuf, oenc);
        k_fused<2, false><<<nblk, 512, 0, stream>>>(x, piw, pib, lyrw, lyrb, gw, gb, pw, pob,
                                                    gbuf, gbuf + 1 * NBAT * HH, oenc);
        k_fused<3, false><<<nblk, 512, 0, stream>>>(x, piw, pib, lyrw, lyrb, gw, gb, pw, pob,
                                                    gbuf, gbuf + 2 * NBAT * HH, oenc);
        k_fused<4, false><<<nblk, 512, 0, stream>>>(x, piw, pib, lyrw, lyrb, gw, gb, pw, pob,
                                                    gbuf, gbuf + 3 * NBAT * HH, oenc);
        k_fused<4, true><<<nblk, 512, 0, stream>>>(x, piw, pib, lyrw, lyrb, gw, gb, pw, pob,
                                                   gbuf, nullptr, oenc);
        k_dec<<<(NBAT * HH) / 256, 256, 0, stream>>>(oenc, out);
    }
}

// Round 10
// 1137.517 us; speedup vs baseline: 1.2508x; 1.2508x over previous
//
#include <hip/hip_runtime.h>

#define HH   64
#define BPTS 256          // points per block/chunk
#define LPB  4096         // points per batch
#define NBAT 256
#define NPTS (NBAT * LPB) // 1,048,576 points

typedef _Float16 f16x8 __attribute__((ext_vector_type(8)));
typedef float    f32x4 __attribute__((ext_vector_type(4)));

union HL { unsigned u; _Float16 f[2]; };

// ======== module-static device scratch (independent of d_ws; BSS, load-time alloc)
__device__ unsigned u_buf[(size_t)NPTS * HH];       // 256 MiB: activations, packed hi|lo f16
__device__ float    partial_buf[(size_t)NPTS * HH]; // 256 MiB: proj_out partial, f32
__device__ float    g_buf[4 * NBAT * HH];           // per-stage batch channel max
__device__ float    goff_buf[4 * NBAT * HH];        // folded glyr g-offsets
__device__ unsigned oenc_buf[NBAT * HH];            // encoded output max

// ---------- swizzled addressing for a [R][64] f16 plane (16B-block XOR)
__device__ __forceinline__ int bofs(int r, int m) {
    return (r << 6) | ((m ^ (r & 7)) << 3);
}
__device__ __forceinline__ int fofs(int r, int c) {
    return (r << 6) | ((((c >> 3) ^ (r & 7))) << 3) | (c & 7);
}
__device__ __forceinline__ f16x8 rd8(const _Float16* p, int r, int m) {
    return *(const f16x8*)&p[bofs(r, m)];
}

// ---------- split-f16: v ~= hi + lo, |v-(hi+lo)| <= 2^-22 |v|
__device__ __forceinline__ void split2(float v, _Float16& h, _Float16& l) {
    h = (_Float16)v;
    l = (_Float16)(v - (float)h);
}
__device__ __forceinline__ unsigned pack_hilo(float v) {
    HL u; split2(v, u.f[0], u.f[1]); return u.u;
}

// ---------- 32x64x64 GEMM tile per wave via MFMA, 3-term split-f16
__device__ __forceinline__ void mfma_gemm(const _Float16* ah_, const _Float16* al_,
                                          const _Float16* wh_, const _Float16* wl_,
                                          int rb, int lane, f32x4 acc[2][4]) {
    const int rA = rb + (lane & 15);
    const int cB = lane & 15;
    const int g  = lane >> 4;
#pragma unroll
    for (int s = 0; s < 2; ++s) {
        const int m = s * 4 + g;
        f16x8 Ah[2], Al[2];
#pragma unroll
        for (int rt = 0; rt < 2; ++rt) {
            Ah[rt] = rd8(ah_, rA + 16 * rt, m);
            Al[rt] = rd8(al_, rA + 16 * rt, m);
        }
#pragma unroll
        for (int ct = 0; ct < 4; ++ct) {
            f16x8 Bh = rd8(wh_, cB + 16 * ct, m);
            f16x8 Bl = rd8(wl_, cB + 16 * ct, m);
#pragma unroll
            for (int rt = 0; rt < 2; ++rt) {
                acc[rt][ct] = __builtin_amdgcn_mfma_f32_16x16x32_f16(Ah[rt], Bh, acc[rt][ct], 0, 0, 0);
                acc[rt][ct] = __builtin_amdgcn_mfma_f32_16x16x32_f16(Ah[rt], Bl, acc[rt][ct], 0, 0, 0);
                acc[rt][ct] = __builtin_amdgcn_mfma_f32_16x16x32_f16(Al[rt], Bh, acc[rt][ct], 0, 0, 0);
            }
        }
    }
}

// ---------- write activations (C/D layout: row=rb+16rt+4g+reg, col=16ct+(lane&15))
__device__ __forceinline__ void write_acts(_Float16* hi, _Float16* lo,
                                           const f32x4 t[2][4], int rb, int lane) {
    const int g = lane >> 4, cb = lane & 15;
#pragma unroll
    for (int rt = 0; rt < 2; ++rt)
#pragma unroll
        for (int reg = 0; reg < 4; ++reg) {
            const int r = rb + 16 * rt + 4 * g + reg;
#pragma unroll
            for (int ct = 0; ct < 4; ++ct) {
                _Float16 h, l;
                split2(t[rt][ct][reg], h, l);
                const int o = fofs(r, 16 * ct + cb);
                hi[o] = h; lo[o] = l;
            }
        }
}

// ---------- stage 64x64 fp32 weight tile -> hi/lo planes (512 threads)
__device__ __forceinline__ void stage_w(_Float16* wh, _Float16* wl,
                                        const float* __restrict__ W, int tid, int ldw) {
    const int o = tid >> 3, k0 = (tid & 7) << 3;
    const float* wr = &W[(size_t)o * ldw + k0];
    float4 a = *(const float4*)wr;
    float4 b = *(const float4*)(wr + 4);
    float v[8] = {a.x, a.y, a.z, a.w, b.x, b.y, b.z, b.w};
    f16x8 h, l;
#pragma unroll
    for (int i = 0; i < 8; ++i) { _Float16 hh, ll; split2(v[i], hh, ll); h[i] = hh; l[i] = ll; }
    const int ofs = bofs(o, k0 >> 3);
    *(f16x8*)&wh[ofs] = h;
    *(f16x8*)&wl[ofs] = l;
}

// ---------- stage packed-u32 activations (global u_buf) -> hi/lo LDS planes
__device__ __forceinline__ void stage_u(_Float16* hi, _Float16* lo, int pbase, int tid) {
    const int row = tid >> 1, c0 = (tid & 1) << 5;
    const unsigned* src = &u_buf[(size_t)(pbase + row) * HH + c0];
#pragma unroll
    for (int j = 0; j < 4; ++j) {
        uint4 qa = *(const uint4*)&src[j * 8];
        uint4 qb = *(const uint4*)&src[j * 8 + 4];
        unsigned q[8] = {qa.x, qa.y, qa.z, qa.w, qb.x, qb.y, qb.z, qb.w};
        f16x8 h, l;
#pragma unroll
        for (int i = 0; i < 8; ++i) { HL v; v.u = q[i]; h[i] = v.f[0]; l[i] = v.f[1]; }
        const int ofs = bofs(row, (c0 >> 3) + j);
        *(f16x8*)&hi[ofs] = h;
        *(f16x8*)&lo[ofs] = l;
    }
}

// ---------- order-preserving float<->uint encoding
__device__ __forceinline__ unsigned encf(float f) {
    unsigned u = __float_as_uint(f);
    return (u & 0x80000000u) ? ~u : (u | 0x80000000u);
}
__device__ __forceinline__ float decf(unsigned u) {
    return (u & 0x80000000u) ? __uint_as_float(u ^ 0x80000000u) : __uint_as_float(~u);
}

__global__ __launch_bounds__(256) void k_init() {
    int i = blockIdx.x * 256 + threadIdx.x;
    if (i < 4 * NBAT * HH) g_buf[i] = 0.0f;
    if (i < NBAT * HH)     oenc_buf[i] = 0x007FFFFFu; // encf(-inf)
}

// ---------- per-(li,batch) goff precompute (proven cheap: ~3us each)
__global__ __launch_bounds__(64) void k_goff(const float* __restrict__ gw,
                                             const float* __restrict__ gb, int li) {
    const int b = blockIdx.x, o = threadIdx.x;
    const float* gr = &g_buf[((size_t)li * NBAT + b) * HH];
    const float* wr = &gw[((size_t)li * 64 + o) * 128 + 64];
    float s = gb[li * 64 + o];
#pragma unroll
    for (int k = 0; k < 64; k += 4) {
        float4 w4 = *(const float4*)&wr[k];
        float4 g4 = *(const float4*)&gr[k];
        s = fmaf(g4.x, w4.x, fmaf(g4.y, w4.y, fmaf(g4.z, w4.z, fmaf(g4.w, w4.w, s))));
    }
    goff_buf[((size_t)li * NBAT + b) * HH + o] = s;
}

// epilogue: reduce m4 (per-thread 4 channels) across lanes+waves, then atomic
#define MAX_EPILOGUE(ATOMIC_STMT)                                               \
    {                                                                           \
        for (int ct = 0; ct < 4; ++ct) {                                        \
            m4[ct] = fmaxf(m4[ct], __shfl_xor(m4[ct], 16, 64));                 \
            m4[ct] = fmaxf(m4[ct], __shfl_xor(m4[ct], 32, 64));                 \
        }                                                                       \
        __syncthreads();                                                        \
        float* red = (float*)a_hi;                                              \
        if ((lane >> 4) == 0)                                                   \
            for (int ct = 0; ct < 4; ++ct)                                      \
                red[wave * 64 + ct * 16 + (lane & 15)] = m4[ct];                \
        __syncthreads();                                                        \
        if (tid < 64) {                                                         \
            float v = red[tid];                                                 \
            for (int w = 1; w < 8; ++w) v = fmaxf(v, red[w * 64 + tid]);        \
            ATOMIC_STMT;                                                        \
        }                                                                       \
    }

// P0: proj_in + lyr0 -> store u0 (packed split-f16), g0-max
__global__ __launch_bounds__(512, 4) void k_p0s(
    const float* __restrict__ x, const float* __restrict__ piw,
    const float* __restrict__ pib, const float* __restrict__ lyrw,
    const float* __restrict__ lyrb) {
    __shared__ __align__(16) _Float16 a_hi[BPTS * HH];
    __shared__ __align__(16) _Float16 a_lo[BPTS * HH];
    __shared__ __align__(16) _Float16 w_hi[HH * HH];
    __shared__ __align__(16) _Float16 w_lo[HH * HH];
    const int tid = threadIdx.x, lane = tid & 63, wave = tid >> 6;
    const int rb = wave << 5;
    const int pbase = blockIdx.x * BPTS;
    const int b = pbase / LPB;
    int ch4[4];
#pragma unroll
    for (int ct = 0; ct < 4; ++ct) ch4[ct] = 16 * ct + (lane & 15);

    stage_w(w_hi, w_lo, lyrw, tid, 64);
    {   // proj_in: 2 threads per point, 32 channels each
        const int p = tid >> 1, half = tid & 1;
        const size_t pidx = (size_t)(pbase + p) * 3;
        const float x0 = x[pidx], x1 = x[pidx + 1], x2 = x[pidx + 2];
#pragma unroll
        for (int j = 0; j < 4; ++j) {
            const int o0 = half * 32 + j * 8;
            f16x8 h, l;
#pragma unroll
            for (int i = 0; i < 8; ++i) {
                const int o = o0 + i;
                float v = fmaxf(fmaf(piw[o * 3], x0,
                              fmaf(piw[o * 3 + 1], x1,
                              fmaf(piw[o * 3 + 2], x2, pib[o]))), 0.0f);
                _Float16 hh, ll; split2(v, hh, ll);
                h[i] = hh; l[i] = ll;
            }
            const int ofs = bofs(p, o0 >> 3);
            *(f16x8*)&a_hi[ofs] = h;
            *(f16x8*)&a_lo[ofs] = l;
        }
    }
    __syncthreads();

    f32x4 acc[2][4];
#pragma unroll
    for (int rt = 0; rt < 2; ++rt)
#pragma unroll
        for (int ct = 0; ct < 4; ++ct) {
            const float bb = lyrb[ch4[ct]];
            acc[rt][ct] = (f32x4){bb, bb, bb, bb};
        }
    mfma_gemm(a_hi, a_lo, w_hi, w_lo, rb, lane, acc);

    const int g = lane >> 4;
    float m4[4] = {0.f, 0.f, 0.f, 0.f};
#pragma unroll
    for (int rt = 0; rt < 2; ++rt)
#pragma unroll
        for (int reg = 0; reg < 4; ++reg) {
            const int r = rb + 16 * rt + 4 * g + reg;
            unsigned* dst = &u_buf[(size_t)(pbase + r) * HH];
#pragma unroll
            for (int ct = 0; ct < 4; ++ct) {
                float v = fmaxf(acc[rt][ct][reg], 0.0f);
                m4[ct] = fmaxf(m4[ct], v);
                dst[ch4[ct]] = pack_hilo(v);
            }
        }
    MAX_EPILOGUE(atomicMax((unsigned*)&g_buf[b * HH + tid], __float_as_uint(v)));
}

// Mid: read u_li -> glyr_li(+goff) -> x_li; pout_li -> partial; lyr_{li+1} -> u, g
__global__ __launch_bounds__(512, 4) void k_midS(
    const float* __restrict__ gw, const float* __restrict__ lyrw,
    const float* __restrict__ lyrb, const float* __restrict__ pw,
    int li, int accflag) {
    __shared__ __align__(16) _Float16 a_hi[BPTS * HH];
    __shared__ __align__(16) _Float16 a_lo[BPTS * HH];
    __shared__ __align__(16) _Float16 w_hi[HH * HH];
    __shared__ __align__(16) _Float16 w_lo[HH * HH];
    const int tid = threadIdx.x, lane = tid & 63, wave = tid >> 6;
    const int rb = wave << 5;
    const int pbase = blockIdx.x * BPTS;
    const int b = pbase / LPB;
    const int g = lane >> 4;
    int ch4[4];
#pragma unroll
    for (int ct = 0; ct < 4; ++ct) ch4[ct] = 16 * ct + (lane & 15);

    stage_u(a_hi, a_lo, pbase, tid);
    stage_w(w_hi, w_lo, &gw[(size_t)li * 64 * 128], tid, 128);
    __syncthreads();

    f32x4 a2[2][4];
#pragma unroll
    for (int ct = 0; ct < 4; ++ct) {
        const float gv = goff_buf[((size_t)li * NBAT + b) * HH + ch4[ct]];
#pragma unroll
        for (int rt = 0; rt < 2; ++rt) a2[rt][ct] = (f32x4){gv, gv, gv, gv};
    }
    mfma_gemm(a_hi, a_lo, w_hi, w_lo, rb, lane, a2);
#pragma unroll
    for (int rt = 0; rt < 2; ++rt)
#pragma unroll
        for (int ct = 0; ct < 4; ++ct)
#pragma unroll
            for (int r = 0; r < 4; ++r)
                a2[rt][ct][r] = fmaxf(a2[rt][ct][r], 0.0f);   // x_li
    __syncthreads();

    write_acts(a_hi, a_lo, a2, rb, lane);
    stage_w(w_hi, w_lo, &pw[(size_t)li * 64], tid, 256);
    __syncthreads();

    f32x4 oacc[2][4];
#pragma unroll
    for (int rt = 0; rt < 2; ++rt)
#pragma unroll
        for (int ct = 0; ct < 4; ++ct) oacc[rt][ct] = (f32x4){0.f, 0.f, 0.f, 0.f};
    mfma_gemm(a_hi, a_lo, w_hi, w_lo, rb, lane, oacc);
#pragma unroll
    for (int rt = 0; rt < 2; ++rt)
#pragma unroll
        for (int reg = 0; reg < 4; ++reg) {
            const int r = rb + 16 * rt + 4 * g + reg;
            float* pr = &partial_buf[(size_t)(pbase + r) * HH];
#pragma unroll
            for (int ct = 0; ct < 4; ++ct) {
                float v = oacc[rt][ct][reg];
                if (accflag) v += pr[ch4[ct]];
                pr[ch4[ct]] = v;
            }
        }
    __syncthreads();
    stage_w(w_hi, w_lo, &lyrw[(size_t)(li + 1) * 4096], tid, 64);
    __syncthreads();

    f32x4 acc[2][4];
#pragma unroll
    for (int rt = 0; rt < 2; ++rt)
#pragma unroll
        for (int ct = 0; ct < 4; ++ct) {
            const float bb = lyrb[(li + 1) * 64 + ch4[ct]];
            acc[rt][ct] = (f32x4){bb, bb, bb, bb};
        }
    mfma_gemm(a_hi, a_lo, w_hi, w_lo, rb, lane, acc);

    float m4[4] = {0.f, 0.f, 0.f, 0.f};
#pragma unroll
    for (int rt = 0; rt < 2; ++rt)
#pragma unroll
        for (int reg = 0; reg < 4; ++reg) {
            const int r = rb + 16 * rt + 4 * g + reg;
            unsigned* dst = &u_buf[(size_t)(pbase + r) * HH];
#pragma unroll
            for (int ct = 0; ct < 4; ++ct) {
                float v = fmaxf(acc[rt][ct][reg], 0.0f);
                m4[ct] = fmaxf(m4[ct], v);
                dst[ch4[ct]] = pack_hilo(v);
            }
        }
    MAX_EPILOGUE(atomicMax((unsigned*)&g_buf[((size_t)(li + 1) * NBAT + b) * HH + tid],
                           __float_as_uint(v)));
}

// Last: read u_3 -> glyr3(+goff3) -> x_3 -> pout3 + partial + pob -> oenc
__global__ __launch_bounds__(512, 4) void k_lastS(
    const float* __restrict__ gw, const float* __restrict__ pw,
    const float* __restrict__ pob) {
    __shared__ __align__(16) _Float16 a_hi[BPTS * HH];
    __shared__ __align__(16) _Float16 a_lo[BPTS * HH];
    __shared__ __align__(16) _Float16 w_hi[HH * HH];
    __shared__ __align__(16) _Float16 w_lo[HH * HH];
    const int tid = threadIdx.x, lane = tid & 63, wave = tid >> 6;
    const int rb = wave << 5;
    const int pbase = blockIdx.x * BPTS;
    const int b = pbase / LPB;
    const int g = lane >> 4;
    const int li = 3;
    int ch4[4];
#pragma unroll
    for (int ct = 0; ct < 4; ++ct) ch4[ct] = 16 * ct + (lane & 15);

    stage_u(a_hi, a_lo, pbase, tid);
    stage_w(w_hi, w_lo, &gw[(size_t)li * 64 * 128], tid, 128);
    __syncthreads();

    f32x4 a2[2][4];
#pragma unroll
    for (int ct = 0; ct < 4; ++ct) {
        const float gv = goff_buf[((size_t)li * NBAT + b) * HH + ch4[ct]];
#pragma unroll
        for (int rt = 0; rt < 2; ++rt) a2[rt][ct] = (f32x4){gv, gv, gv, gv};
    }
    mfma_gemm(a_hi, a_lo, w_hi, w_lo, rb, lane, a2);
#pragma unroll
    for (int rt = 0; rt < 2; ++rt)
#pragma unroll
        for (int ct = 0; ct < 4; ++ct)
#pragma unroll
            for (int r = 0; r < 4; ++r)
                a2[rt][ct][r] = fmaxf(a2[rt][ct][r], 0.0f);
    __syncthreads();

    write_acts(a_hi, a_lo, a2, rb, lane);
    stage_w(w_hi, w_lo, &pw[(size_t)li * 64], tid, 256);
    __syncthreads();

    f32x4 oacc[2][4];
#pragma unroll
    for (int rt = 0; rt < 2; ++rt)
#pragma unroll
        for (int ct = 0; ct < 4; ++ct) oacc[rt][ct] = (f32x4){0.f, 0.f, 0.f, 0.f};
    mfma_gemm(a_hi, a_lo, w_hi, w_lo, rb, lane, oacc);

    float m4[4] = {-3.4e38f, -3.4e38f, -3.4e38f, -3.4e38f};
#pragma unroll
    for (int rt = 0; rt < 2; ++rt)
#pragma unroll
        for (int reg = 0; reg < 4; ++reg) {
            const int r = rb + 16 * rt + 4 * g + reg;
            const float* pr = &partial_buf[(size_t)(pbase + r) * HH];
#pragma unroll
            for (int ct = 0; ct < 4; ++ct)
                m4[ct] = fmaxf(m4[ct], oacc[rt][ct][reg] + pr[ch4[ct]]);
        }
    MAX_EPILOGUE(atomicMax(&oenc_buf[b * HH + tid], encf(v + pob[tid])));
}

__global__ __launch_bounds__(256) void k_dec(float* __restrict__ out) {
    int i = blockIdx.x * 256 + threadIdx.x;
    out[i] = decf(oenc_buf[i]);
}

extern "C" void kernel_launch(void* const* d_in, const int* in_sizes, int n_in,
                              void* d_out, int out_size, void* d_ws, size_t ws_size,
                              hipStream_t stream) {
    const float* x    = (const float*)d_in[0];
    const float* piw  = (const float*)d_in[1];
    const float* pib  = (const float*)d_in[2];
    const float* lyrw = (const float*)d_in[3];
    const float* lyrb = (const float*)d_in[4];
    const float* gw   = (const float*)d_in[5];
    const float* gb   = (const float*)d_in[6];
    const float* pw   = (const float*)d_in[7];
    const float* pob  = (const float*)d_in[8];
    float* out = (float*)d_out;

    const int nblk = NPTS / BPTS; // 4096

    k_init<<<256, 256, 0, stream>>>();
    k_p0s<<<nblk, 512, 0, stream>>>(x, piw, pib, lyrw, lyrb);

    k_goff<<<NBAT, 64, 0, stream>>>(gw, gb, 0);
    k_midS<<<nblk, 512, 0, stream>>>(gw, lyrw, lyrb, pw, 0, 0);

    k_goff<<<NBAT, 64, 0, stream>>>(gw, gb, 1);
    k_midS<<<nblk, 512, 0, stream>>>(gw, lyrw, lyrb, pw, 1, 1);

    k_goff<<<NBAT, 64, 0, stream>>>(gw, gb, 2);
    k_midS<<<nblk, 512, 0, stream>>>(gw, lyrw, lyrb, pw, 2, 1);

    k_goff<<<NBAT, 64, 0, stream>>>(gw, gb, 3);
    k_lastS<<<nblk, 512, 0, stream>>>(gw, pw, pob);

    k_dec<<<(NBAT * HH) / 256, 256, 0, stream>>>(out);
}